// Round 3
// baseline (731.726 us; speedup 1.0000x reference)
//
#include <hip/hip_runtime.h>
#include <math.h>
#include <float.h>

#define N_NODES 50000
#define N_EDGES 800000
#define D_INP   96
#define D_HID   128
#define N_B     512
#define SCAN_NB 98   // ceil(50000/512)
#define CHUNKS  8    // 128 feats / 16 per chunk

// ---------------------------------------------------------------------------
__global__ void k_transpose(const float* __restrict__ W_in,
                            const float* __restrict__ W_ih,
                            const float* __restrict__ W_hh,
                            float* __restrict__ Wt_in,
                            float* __restrict__ Wt_g) {
    int idx = blockIdx.x * 256 + threadIdx.x;
    if (idx < D_INP * D_HID) {
        int k = idx / D_HID, d = idx % D_HID;
        Wt_in[idx] = W_in[d * D_INP + k];
    }
    if (idx < 384 * 512) {
        int k = idx / 512, g = idx % 512;
        Wt_g[idx] = (k < 256) ? W_ih[g * 256 + k] : W_hh[g * 128 + (k - 256)];
    }
}

// ---------------------------------------------------------------------------
__global__ void k_count(const int* __restrict__ dst, int* __restrict__ cnt) {
    int e = blockIdx.x * 256 + threadIdx.x;
    if (e < N_EDGES) atomicAdd(&cnt[dst[e]], 1);
}

__global__ __launch_bounds__(512) void k_scan_block(const int* __restrict__ cnt,
                                                    int* __restrict__ row_ptr,
                                                    int* __restrict__ partials,
                                                    float* __restrict__ deg_f) {
    __shared__ int sm[512];
    int i = blockIdx.x * 512 + threadIdx.x;
    int v = (i < N_NODES) ? cnt[i] : 0;
    sm[threadIdx.x] = v;
    __syncthreads();
    for (int off = 1; off < 512; off <<= 1) {
        int u = (threadIdx.x >= off) ? sm[threadIdx.x - off] : 0;
        __syncthreads();
        sm[threadIdx.x] += u;
        __syncthreads();
    }
    if (i < N_NODES) {
        row_ptr[i] = sm[threadIdx.x] - v;
        deg_f[i] = (float)max(v, 1);
    }
    if (threadIdx.x == 511) partials[blockIdx.x] = sm[511];
}

__global__ __launch_bounds__(128) void k_scan_part(int* __restrict__ partials,
                                                   int* __restrict__ row_ptr) {
    __shared__ int sm[128];
    int t = threadIdx.x;
    int v = (t < SCAN_NB) ? partials[t] : 0;
    sm[t] = v;
    __syncthreads();
    for (int off = 1; off < 128; off <<= 1) {
        int u = (t >= off) ? sm[t - off] : 0;
        __syncthreads();
        sm[t] += u;
        __syncthreads();
    }
    if (t < SCAN_NB) partials[t] = sm[t] - v;
    if (t == 127) row_ptr[N_NODES] = sm[127];
}

__global__ __launch_bounds__(512) void k_scan_add(int* __restrict__ row_ptr,
                                                  const int* __restrict__ partials,
                                                  int* __restrict__ cnt) {
    int i = blockIdx.x * 512 + threadIdx.x;
    if (i < N_NODES) {
        row_ptr[i] += partials[blockIdx.x];
        cnt[i] = 0;
    }
}

__global__ void k_scatter(const int* __restrict__ src, const int* __restrict__ dst,
                          const int* __restrict__ row_ptr, int* __restrict__ cnt,
                          int* __restrict__ esrc) {
    int e = blockIdx.x * 256 + threadIdx.x;
    if (e < N_EDGES) {
        int d = dst[e];
        int p = row_ptr[d] + atomicAdd(&cnt[d], 1);
        esrc[p] = src[e];
    }
}

__global__ void k_segptr(const int* __restrict__ batch, int* __restrict__ seg_ptr) {
    int n = blockIdx.x * 256 + threadIdx.x;
    if (n >= N_NODES) return;
    int bc = batch[n];
    int bp = (n == 0) ? -1 : batch[n - 1];
    for (int b = bp + 1; b <= bc; b++) seg_ptr[b] = n;
    if (n == N_NODES - 1)
        for (int b = bc + 1; b <= N_B; b++) seg_ptr[b] = N_NODES;
}

// ---------------------------------------------------------------------------
// Input layer: writes CHUNK-MAJOR ht[c][node][16]
__global__ __launch_bounds__(256) void k_ingemm(const float* __restrict__ x,
                                                const float* __restrict__ Wt_in,
                                                const float* __restrict__ b_in,
                                                float* __restrict__ ht) {
    __shared__ __align__(16) float xs[64 * 96];
    __shared__ __align__(16) float ws[96 * 64];
    int n0 = blockIdx.x * 64;
    int d0 = blockIdx.y * 64;
    int tid = threadIdx.x;
    for (int j = tid; j < 64 * 96 / 4; j += 256) {
        int node = n0 + (j * 4) / 96;
        float4 v = make_float4(0.f, 0.f, 0.f, 0.f);
        if (node < N_NODES) v = *(const float4*)&x[n0 * 96 + j * 4];
        *(float4*)&xs[j * 4] = v;
    }
    for (int j = tid; j < 96 * 64 / 4; j += 256) {
        int k = (j * 4) / 64, dd = (j * 4) % 64;
        *(float4*)&ws[j * 4] = *(const float4*)&Wt_in[k * D_HID + d0 + dd];
    }
    __syncthreads();
    int tn = tid / 16;
    int td = tid % 16;
    float acc[4][4] = {};
    for (int k0 = 0; k0 < 96; k0 += 4) {
        float4 w0 = *(float4*)&ws[(k0 + 0) * 64 + td * 4];
        float4 w1 = *(float4*)&ws[(k0 + 1) * 64 + td * 4];
        float4 w2 = *(float4*)&ws[(k0 + 2) * 64 + td * 4];
        float4 w3 = *(float4*)&ws[(k0 + 3) * 64 + td * 4];
#pragma unroll
        for (int j = 0; j < 4; j++) {
            float4 xv = *(float4*)&xs[(tn * 4 + j) * 96 + k0];
            acc[j][0] += xv.x * w0.x + xv.y * w1.x + xv.z * w2.x + xv.w * w3.x;
            acc[j][1] += xv.x * w0.y + xv.y * w1.y + xv.z * w2.y + xv.w * w3.y;
            acc[j][2] += xv.x * w0.z + xv.y * w1.z + xv.z * w2.z + xv.w * w3.z;
            acc[j][3] += xv.x * w0.w + xv.y * w1.w + xv.z * w2.w + xv.w * w3.w;
        }
    }
    float4 bb = *(const float4*)&b_in[d0 + td * 4];
    int dd = d0 + td * 4;
    int c = dd >> 4, jj = dd & 15;
#pragma unroll
    for (int j = 0; j < 4; j++) {
        int node = n0 + tn * 4 + j;
        if (node < N_NODES) {
            float4 o;
            o.x = fmaxf(acc[j][0] + bb.x, 0.f);
            o.y = fmaxf(acc[j][1] + bb.y, 0.f);
            o.z = fmaxf(acc[j][2] + bb.z, 0.f);
            o.w = fmaxf(acc[j][3] + bb.w, 0.f);
            *(float4*)&ht[((size_t)c * N_NODES + node) * 16 + jj] = o;
        }
    }
}

// ---------------------------------------------------------------------------
// Chunked MPNN step. hin is chunk-major [8][N][16]. blockIdx.y = chunk
// (slowest-varying -> all XCDs stream the same 3.2 MB chunk: L2-resident).
// 4 lanes x float4 = one 64 B chunk row per node-group.
template <bool ROWMAJOR_OUT>
__global__ __launch_bounds__(256) void k_mpnn_c(const float* __restrict__ hin,
                                                float* __restrict__ hout,
                                                const int* __restrict__ row_ptr,
                                                const int* __restrict__ esrc,
                                                const float* __restrict__ deg_f) {
    int c = blockIdx.y;
    int grp = threadIdx.x >> 2;
    int l = threadIdx.x & 3;
    int n = blockIdx.x * 64 + grp;
    if (n >= N_NODES) return;
    const float* base = hin + (size_t)c * (N_NODES * 16);
    int s0 = row_ptr[n], s1 = row_ptr[n + 1];
    float4 acc = make_float4(0.f, 0.f, 0.f, 0.f);
    for (int i = s0; i < s1; i++) {
        int s = esrc[i];
        float4 v = *(const float4*)&base[s * 16 + l * 4];
        acc.x += v.x; acc.y += v.y; acc.z += v.z; acc.w += v.w;
    }
    float invd = 1.0f / deg_f[n];
    float4 hv = *(const float4*)&base[n * 16 + l * 4];
    float4 o;
    o.x = (hv.x + acc.x * invd) * 0.5f;
    o.y = (hv.y + acc.y * invd) * 0.5f;
    o.z = (hv.z + acc.z * invd) * 0.5f;
    o.w = (hv.w + acc.w * invd) * 0.5f;
    if (ROWMAJOR_OUT)
        *(float4*)&hout[(size_t)n * 128 + c * 16 + l * 4] = o;
    else
        *(float4*)&hout[((size_t)c * N_NODES + n) * 16 + l * 4] = o;
}

// ---------------------------------------------------------------------------
__global__ __launch_bounds__(128) void k_gates(const float* __restrict__ qstar,
                                               const float* __restrict__ hh,
                                               const float* __restrict__ Wt_g,
                                               const float* __restrict__ b_ih,
                                               const float* __restrict__ b_hh,
                                               float* __restrict__ gates) {
    __shared__ __align__(16) float als[4 * 384];
    int b0 = blockIdx.x * 4;
    int g0 = blockIdx.y * 256;
    int tid = threadIdx.x;
    for (int i = tid; i < 4 * 384; i += 128) {
        int bb = i / 384, k = i % 384;
        als[i] = (k < 256) ? qstar[(b0 + bb) * 256 + k]
                           : hh[(b0 + bb) * 128 + (k - 256)];
    }
    __syncthreads();
    int g = g0 + tid * 2;
    float2 acc0 = {0.f, 0.f}, acc1 = {0.f, 0.f}, acc2 = {0.f, 0.f}, acc3 = {0.f, 0.f};
    for (int k0 = 0; k0 < 384; k0 += 4) {
        float4 a0 = *(float4*)&als[0 * 384 + k0];
        float4 a1 = *(float4*)&als[1 * 384 + k0];
        float4 a2 = *(float4*)&als[2 * 384 + k0];
        float4 a3 = *(float4*)&als[3 * 384 + k0];
        float2 w;
        w = *(const float2*)&Wt_g[(k0 + 0) * 512 + g];
        acc0.x += a0.x * w.x; acc0.y += a0.x * w.y;
        acc1.x += a1.x * w.x; acc1.y += a1.x * w.y;
        acc2.x += a2.x * w.x; acc2.y += a2.x * w.y;
        acc3.x += a3.x * w.x; acc3.y += a3.x * w.y;
        w = *(const float2*)&Wt_g[(k0 + 1) * 512 + g];
        acc0.x += a0.y * w.x; acc0.y += a0.y * w.y;
        acc1.x += a1.y * w.x; acc1.y += a1.y * w.y;
        acc2.x += a2.y * w.x; acc2.y += a2.y * w.y;
        acc3.x += a3.y * w.x; acc3.y += a3.y * w.y;
        w = *(const float2*)&Wt_g[(k0 + 2) * 512 + g];
        acc0.x += a0.z * w.x; acc0.y += a0.z * w.y;
        acc1.x += a1.z * w.x; acc1.y += a1.z * w.y;
        acc2.x += a2.z * w.x; acc2.y += a2.z * w.y;
        acc3.x += a3.z * w.x; acc3.y += a3.z * w.y;
        w = *(const float2*)&Wt_g[(k0 + 3) * 512 + g];
        acc0.x += a0.w * w.x; acc0.y += a0.w * w.y;
        acc1.x += a1.w * w.x; acc1.y += a1.w * w.y;
        acc2.x += a2.w * w.x; acc2.y += a2.w * w.y;
        acc3.x += a3.w * w.x; acc3.y += a3.w * w.y;
    }
    float bias0 = b_ih[g] + b_hh[g];
    float bias1 = b_ih[g + 1] + b_hh[g + 1];
    float2 o;
    o.x = acc0.x + bias0; o.y = acc0.y + bias1;
    *(float2*)&gates[(b0 + 0) * 512 + g] = o;
    o.x = acc1.x + bias0; o.y = acc1.y + bias1;
    *(float2*)&gates[(b0 + 1) * 512 + g] = o;
    o.x = acc2.x + bias0; o.y = acc2.y + bias1;
    *(float2*)&gates[(b0 + 2) * 512 + g] = o;
    o.x = acc3.x + bias0; o.y = acc3.y + bias1;
    *(float2*)&gates[(b0 + 3) * 512 + g] = o;
}

__device__ __forceinline__ float sigmoidf_(float v) { return 1.0f / (1.0f + expf(-v)); }

__global__ void k_lstm(const float* __restrict__ gates, float* __restrict__ hh,
                       float* __restrict__ cc, float* __restrict__ qstar) {
    int idx = blockIdx.x * 256 + threadIdx.x;
    int b = idx >> 7, dd = idx & 127;
    const float* gr = &gates[b * 512];
    float ig = gr[dd], fg = gr[128 + dd], gg = gr[256 + dd], og = gr[384 + dd];
    float c = sigmoidf_(fg) * cc[idx] + sigmoidf_(ig) * tanhf(gg);
    cc[idx] = c;
    float hv = sigmoidf_(og) * tanhf(c);
    hh[idx] = hv;
    qstar[b * 256 + dd] = hv;
}

// Online-softmax segment attention: SINGLE pass over h.
__global__ __launch_bounds__(128) void k_attn(const float* __restrict__ h,
                                              const float* __restrict__ hh,
                                              const int* __restrict__ seg_ptr,
                                              float* __restrict__ qstar) {
    int b = blockIdx.x;
    int g = threadIdx.x >> 5, l = threadIdx.x & 31;
    int s0 = seg_ptr[b], s1 = seg_ptr[b + 1];
    float4 q = *(const float4*)&hh[b * 128 + l * 4];
    float M = -INFINITY, asum = 0.f;
    float4 racc = make_float4(0.f, 0.f, 0.f, 0.f);
    for (int n = s0 + g; n < s1; n += 4) {
        float4 hv = *(const float4*)&h[(size_t)n * 128 + l * 4];
        float d = hv.x * q.x + hv.y * q.y + hv.z * q.z + hv.w * q.w;
        for (int m = 16; m >= 1; m >>= 1) d += __shfl_xor(d, m, 64);
        float newM = fmaxf(M, d);
        float scale = expf(M - newM);     // 0 on first iter (M = -inf)
        float a = expf(d - newM);
        asum = asum * scale + a;
        racc.x = racc.x * scale + a * hv.x;
        racc.y = racc.y * scale + a * hv.y;
        racc.z = racc.z * scale + a * hv.z;
        racc.w = racc.w * scale + a * hv.w;
        M = newM;
    }
    __shared__ float smax[4];
    __shared__ float ssum[4];
    __shared__ __align__(16) float sr[4][128];
    if (l == 0) { smax[g] = M; ssum[g] = asum; }
    *(float4*)&sr[g][l * 4] = racc;
    __syncthreads();
    if (g == 0) {
        float Mx = fmaxf(fmaxf(smax[0], smax[1]), fmaxf(smax[2], smax[3]));
        float4 o = make_float4(0.f, 0.f, 0.f, 0.f);
        if (Mx > -INFINITY) {
            float w0 = expf(smax[0] - Mx), w1 = expf(smax[1] - Mx);
            float w2 = expf(smax[2] - Mx), w3 = expf(smax[3] - Mx);
            float tot = ssum[0] * w0 + ssum[1] * w1 + ssum[2] * w2 + ssum[3] * w3;
            float inv = 1.0f / (tot + 1e-16f);
            float4 r0 = *(float4*)&sr[0][l * 4];
            float4 r1 = *(float4*)&sr[1][l * 4];
            float4 r2 = *(float4*)&sr[2][l * 4];
            float4 r3 = *(float4*)&sr[3][l * 4];
            o.x = (r0.x * w0 + r1.x * w1 + r2.x * w2 + r3.x * w3) * inv;
            o.y = (r0.y * w0 + r1.y * w1 + r2.y * w2 + r3.y * w3) * inv;
            o.z = (r0.z * w0 + r1.z * w1 + r2.z * w2 + r3.z * w3) * inv;
            o.w = (r0.w * w0 + r1.w * w1 + r2.w * w2 + r3.w * w3) * inv;
        }
        *(float4*)&qstar[b * 256 + 128 + l * 4] = o;
    }
}

__global__ void k_pred(const float* __restrict__ qstar, const float* __restrict__ W_pred,
                       const float* __restrict__ b_pred, float* __restrict__ out) {
    int w = (blockIdx.x * 256 + threadIdx.x) >> 6;
    int l = threadIdx.x & 63;
    if (w >= N_B) return;
    float4 qv = *(const float4*)&qstar[w * 256 + l * 4];
    float4 wv = *(const float4*)&W_pred[l * 4];
    float d = qv.x * wv.x + qv.y * wv.y + qv.z * wv.z + qv.w * wv.w;
    for (int m = 32; m >= 1; m >>= 1) d += __shfl_xor(d, m, 64);
    if (l == 0) out[w] = d + b_pred[0];
}

// ---------------------------------------------------------------------------
extern "C" void kernel_launch(void* const* d_in, const int* in_sizes, int n_in,
                              void* d_out, int out_size, void* d_ws, size_t ws_size,
                              hipStream_t stream) {
    const float* x      = (const float*)d_in[0];
    const int*   edge   = (const int*)d_in[1];
    const int*   batch  = (const int*)d_in[2];
    const float* W_in   = (const float*)d_in[3];
    const float* b_in   = (const float*)d_in[4];
    const float* W_ih   = (const float*)d_in[5];
    const float* W_hh   = (const float*)d_in[6];
    const float* b_ih   = (const float*)d_in[7];
    const float* b_hh   = (const float*)d_in[8];
    const float* W_pred = (const float*)d_in[9];
    const float* b_pred = (const float*)d_in[10];
    float* out = (float*)d_out;

    const int* src = edge;
    const int* dst = edge + N_EDGES;

    // workspace: bufA serves as ht0 (chunk-major) during MPNN and as the final
    // row-major h afterwards (step 4 reads bufB, writes bufA row-major).
    float* f = (float*)d_ws;
    float* bufA  = f;                     f += (size_t)N_NODES * D_HID;
    float* bufB  = f;                     f += (size_t)N_NODES * D_HID;
    float* deg_f = f;                     f += N_NODES;
    float* qstar = f;                     f += (size_t)N_B * 256;
    float* hh    = f;                     f += (size_t)N_B * 128;
    float* cc    = f;                     f += (size_t)N_B * 128;
    float* gates = f;                     f += (size_t)N_B * 512;
    float* Wt_in = f;                     f += D_INP * D_HID;
    float* Wt_g  = f;                     f += 384 * 512;
    int* ip = (int*)f;
    int* row_ptr = ip;                    ip += N_NODES + 1;
    int* cnt     = ip;                    ip += N_NODES;
    int* esrc    = ip;                    ip += N_EDGES;
    int* seg_ptr = ip;                    ip += N_B + 1;
    int* partials = ip;                   ip += 128;

    // ---- CSR build + seg_ptr + weight transposes
    hipMemsetAsync(cnt, 0, N_NODES * sizeof(int), stream);
    k_transpose<<<768, 256, 0, stream>>>(W_in, W_ih, W_hh, Wt_in, Wt_g);
    k_count<<<(N_EDGES + 255) / 256, 256, 0, stream>>>(dst, cnt);
    k_scan_block<<<SCAN_NB, 512, 0, stream>>>(cnt, row_ptr, partials, deg_f);
    k_scan_part<<<1, 128, 0, stream>>>(partials, row_ptr);
    k_scan_add<<<SCAN_NB, 512, 0, stream>>>(row_ptr, partials, cnt);  // also zeroes cnt
    k_scatter<<<(N_EDGES + 255) / 256, 256, 0, stream>>>(src, dst, row_ptr, cnt, esrc);
    k_segptr<<<(N_NODES + 255) / 256, 256, 0, stream>>>(batch, seg_ptr);

    // ---- input layer (writes chunk-major into bufA)
    k_ingemm<<<dim3((N_NODES + 63) / 64, 2), 256, 0, stream>>>(x, Wt_in, b_in, bufA);

    // ---- 4 MPNN steps, chunk-major grid; last step emits row-major into bufA
    dim3 mg((N_NODES + 63) / 64, CHUNKS);
    k_mpnn_c<false><<<mg, 256, 0, stream>>>(bufA, bufB, row_ptr, esrc, deg_f);
    k_mpnn_c<false><<<mg, 256, 0, stream>>>(bufB, bufA, row_ptr, esrc, deg_f);
    k_mpnn_c<false><<<mg, 256, 0, stream>>>(bufA, bufB, row_ptr, esrc, deg_f);
    k_mpnn_c<true ><<<mg, 256, 0, stream>>>(bufB, bufA, row_ptr, esrc, deg_f);

    // ---- Set2Set
    hipMemsetAsync(qstar, 0, (size_t)(N_B * 256 + N_B * 128 + N_B * 128) * sizeof(float), stream);
    for (int step = 0; step < 3; step++) {
        k_gates<<<dim3(N_B / 4, 2), 128, 0, stream>>>(qstar, hh, Wt_g, b_ih, b_hh, gates);
        k_lstm<<<(N_B * 128) / 256, 256, 0, stream>>>(gates, hh, cc, qstar);
        k_attn<<<N_B, 128, 0, stream>>>(bufA, hh, seg_ptr, qstar);
    }

    // ---- prediction head
    k_pred<<<(N_B * 64) / 256, 256, 0, stream>>>(qstar, W_pred, b_pred, out);
}

// Round 4
// 573.526 us; speedup vs baseline: 1.2758x; 1.2758x over previous
//
#include <hip/hip_runtime.h>
#include <math.h>
#include <float.h>

#define N_NODES 50000
#define N_EDGES 800000
#define D_INP   96
#define D_HID   128
#define N_B     512
#define SCAN_NB 98   // ceil(50000/512)

// ---------------------------------------------------------------------------
// Weight transposes + zero cnt (folded in to save a memset dispatch)
__global__ void k_transpose(const float* __restrict__ W_in,
                            const float* __restrict__ W_ih,
                            const float* __restrict__ W_hh,
                            float* __restrict__ Wt_in,
                            float* __restrict__ Wt_g,
                            int* __restrict__ cnt) {
    int idx = blockIdx.x * 256 + threadIdx.x;
    if (idx < N_NODES) cnt[idx] = 0;
    if (idx < D_INP * D_HID) {
        int k = idx / D_HID, d = idx % D_HID;
        Wt_in[idx] = W_in[d * D_INP + k];
    }
    if (idx < 384 * 512) {
        int k = idx / 512, g = idx % 512;
        Wt_g[idx] = (k < 256) ? W_ih[g * 256 + k] : W_hh[g * 128 + (k - 256)];
    }
}

// ---------------------------------------------------------------------------
__global__ void k_count(const int* __restrict__ dst, int* __restrict__ cnt) {
    int e = blockIdx.x * 256 + threadIdx.x;
    if (e < N_EDGES) atomicAdd(&cnt[dst[e]], 1);
}

__global__ __launch_bounds__(512) void k_scan_block(const int* __restrict__ cnt,
                                                    int* __restrict__ row_ptr,
                                                    int* __restrict__ partials,
                                                    float* __restrict__ deg_f) {
    __shared__ int sm[512];
    int i = blockIdx.x * 512 + threadIdx.x;
    int v = (i < N_NODES) ? cnt[i] : 0;
    sm[threadIdx.x] = v;
    __syncthreads();
    for (int off = 1; off < 512; off <<= 1) {
        int u = (threadIdx.x >= off) ? sm[threadIdx.x - off] : 0;
        __syncthreads();
        sm[threadIdx.x] += u;
        __syncthreads();
    }
    if (i < N_NODES) {
        row_ptr[i] = sm[threadIdx.x] - v;
        deg_f[i] = (float)max(v, 1);
    }
    if (threadIdx.x == 511) partials[blockIdx.x] = sm[511];
}

__global__ __launch_bounds__(128) void k_scan_part(int* __restrict__ partials,
                                                   int* __restrict__ row_ptr) {
    __shared__ int sm[128];
    int t = threadIdx.x;
    int v = (t < SCAN_NB) ? partials[t] : 0;
    sm[t] = v;
    __syncthreads();
    for (int off = 1; off < 128; off <<= 1) {
        int u = (t >= off) ? sm[t - off] : 0;
        __syncthreads();
        sm[t] += u;
        __syncthreads();
    }
    if (t < SCAN_NB) partials[t] = sm[t] - v;
    if (t == 127) row_ptr[N_NODES] = sm[127];
}

__global__ __launch_bounds__(512) void k_scan_add(int* __restrict__ row_ptr,
                                                  const int* __restrict__ partials,
                                                  int* __restrict__ cnt) {
    int i = blockIdx.x * 512 + threadIdx.x;
    if (i < N_NODES) {
        row_ptr[i] += partials[blockIdx.x];
        cnt[i] = 0;
    }
}

__global__ void k_scatter(const int* __restrict__ src, const int* __restrict__ dst,
                          const int* __restrict__ row_ptr, int* __restrict__ cnt,
                          int* __restrict__ esrc) {
    int e = blockIdx.x * 256 + threadIdx.x;
    if (e < N_EDGES) {
        int d = dst[e];
        int p = row_ptr[d] + atomicAdd(&cnt[d], 1);
        esrc[p] = src[e];
    }
}

__global__ void k_segptr(const int* __restrict__ batch, int* __restrict__ seg_ptr) {
    int n = blockIdx.x * 256 + threadIdx.x;
    if (n >= N_NODES) return;
    int bc = batch[n];
    int bp = (n == 0) ? -1 : batch[n - 1];
    for (int b = bp + 1; b <= bc; b++) seg_ptr[b] = n;
    if (n == N_NODES - 1)
        for (int b = bc + 1; b <= N_B; b++) seg_ptr[b] = N_NODES;
}

// ---------------------------------------------------------------------------
// Input layer (row-major out). Also zero-inits the Set2Set state block
// (qstar|hh|cc contiguous, 262144 floats) to save a memset dispatch.
__global__ __launch_bounds__(256) void k_ingemm(const float* __restrict__ x,
                                                const float* __restrict__ Wt_in,
                                                const float* __restrict__ b_in,
                                                float* __restrict__ h,
                                                float* __restrict__ zbase) {
    int gid = ((blockIdx.y * gridDim.x) + blockIdx.x) * 256 + threadIdx.x;
    if (gid < N_B * 512) zbase[gid] = 0.f;

    __shared__ __align__(16) float xs[64 * 96];
    __shared__ __align__(16) float ws[96 * 64];
    int n0 = blockIdx.x * 64;
    int d0 = blockIdx.y * 64;
    int tid = threadIdx.x;
    for (int j = tid; j < 64 * 96 / 4; j += 256) {
        int node = n0 + (j * 4) / 96;
        float4 v = make_float4(0.f, 0.f, 0.f, 0.f);
        if (node < N_NODES) v = *(const float4*)&x[n0 * 96 + j * 4];
        *(float4*)&xs[j * 4] = v;
    }
    for (int j = tid; j < 96 * 64 / 4; j += 256) {
        int k = (j * 4) / 64, dd = (j * 4) % 64;
        *(float4*)&ws[j * 4] = *(const float4*)&Wt_in[k * D_HID + d0 + dd];
    }
    __syncthreads();
    int tn = tid / 16;
    int td = tid % 16;
    float acc[4][4] = {};
    for (int k0 = 0; k0 < 96; k0 += 4) {
        float4 w0 = *(float4*)&ws[(k0 + 0) * 64 + td * 4];
        float4 w1 = *(float4*)&ws[(k0 + 1) * 64 + td * 4];
        float4 w2 = *(float4*)&ws[(k0 + 2) * 64 + td * 4];
        float4 w3 = *(float4*)&ws[(k0 + 3) * 64 + td * 4];
#pragma unroll
        for (int j = 0; j < 4; j++) {
            float4 xv = *(float4*)&xs[(tn * 4 + j) * 96 + k0];
            acc[j][0] += xv.x * w0.x + xv.y * w1.x + xv.z * w2.x + xv.w * w3.x;
            acc[j][1] += xv.x * w0.y + xv.y * w1.y + xv.z * w2.y + xv.w * w3.y;
            acc[j][2] += xv.x * w0.z + xv.y * w1.z + xv.z * w2.z + xv.w * w3.z;
            acc[j][3] += xv.x * w0.w + xv.y * w1.w + xv.z * w2.w + xv.w * w3.w;
        }
    }
    float4 bb = *(const float4*)&b_in[d0 + td * 4];
#pragma unroll
    for (int j = 0; j < 4; j++) {
        int node = n0 + tn * 4 + j;
        if (node < N_NODES) {
            float4 o;
            o.x = fmaxf(acc[j][0] + bb.x, 0.f);
            o.y = fmaxf(acc[j][1] + bb.y, 0.f);
            o.z = fmaxf(acc[j][2] + bb.z, 0.f);
            o.w = fmaxf(acc[j][3] + bb.w, 0.f);
            *(float4*)&h[(size_t)node * D_HID + d0 + td * 4] = o;
        }
    }
}

// ---------------------------------------------------------------------------
// MPNN step, row-major, edge loop unrolled x4 (4 independent in-flight
// 512B gathers per 32-lane group) to raise memory-level parallelism.
__global__ __launch_bounds__(256) void k_mpnn(const float* __restrict__ hin,
                                              float* __restrict__ hout,
                                              const int* __restrict__ row_ptr,
                                              const int* __restrict__ esrc,
                                              const float* __restrict__ deg_f) {
    int g = threadIdx.x >> 5;
    int l = threadIdx.x & 31;
    int n = blockIdx.x * 8 + g;
    if (n >= N_NODES) return;
    int s0 = row_ptr[n], s1 = row_ptr[n + 1];
    float4 a0 = {0,0,0,0}, a1 = {0,0,0,0}, a2 = {0,0,0,0}, a3 = {0,0,0,0};
    int i = s0;
    for (; i + 4 <= s1; i += 4) {
        int e0 = esrc[i + 0];
        int e1 = esrc[i + 1];
        int e2 = esrc[i + 2];
        int e3 = esrc[i + 3];
        float4 v0 = *(const float4*)&hin[(size_t)e0 * 128 + l * 4];
        float4 v1 = *(const float4*)&hin[(size_t)e1 * 128 + l * 4];
        float4 v2 = *(const float4*)&hin[(size_t)e2 * 128 + l * 4];
        float4 v3 = *(const float4*)&hin[(size_t)e3 * 128 + l * 4];
        a0.x += v0.x; a0.y += v0.y; a0.z += v0.z; a0.w += v0.w;
        a1.x += v1.x; a1.y += v1.y; a1.z += v1.z; a1.w += v1.w;
        a2.x += v2.x; a2.y += v2.y; a2.z += v2.z; a2.w += v2.w;
        a3.x += v3.x; a3.y += v3.y; a3.z += v3.z; a3.w += v3.w;
    }
    for (; i < s1; i++) {
        int e0 = esrc[i];
        float4 v0 = *(const float4*)&hin[(size_t)e0 * 128 + l * 4];
        a0.x += v0.x; a0.y += v0.y; a0.z += v0.z; a0.w += v0.w;
    }
    a0.x += a1.x + a2.x + a3.x;
    a0.y += a1.y + a2.y + a3.y;
    a0.z += a1.z + a2.z + a3.z;
    a0.w += a1.w + a2.w + a3.w;
    float invd = 1.0f / deg_f[n];
    float4 hv = *(const float4*)&hin[(size_t)n * 128 + l * 4];
    float4 o;
    o.x = (hv.x + a0.x * invd) * 0.5f;
    o.y = (hv.y + a0.y * invd) * 0.5f;
    o.z = (hv.z + a0.z * invd) * 0.5f;
    o.w = (hv.w + a0.w * invd) * 0.5f;
    *(float4*)&hout[(size_t)n * 128 + l * 4] = o;
}

__device__ __forceinline__ float sigmoidf_(float v) { return 1.0f / (1.0f + expf(-v)); }

// ---------------------------------------------------------------------------
// Fused gates GEMM + LSTM. One block handles 4 batch rows, all 512 gates.
// 128 threads: thread t computes gates [t*4, t*4+4) for each of 4 rows.
__global__ __launch_bounds__(128) void k_gates_lstm(float* __restrict__ qstar,
                                                    float* __restrict__ hh,
                                                    float* __restrict__ cc,
                                                    const float* __restrict__ Wt_g,
                                                    const float* __restrict__ b_ih,
                                                    const float* __restrict__ b_hh) {
    __shared__ __align__(16) float als[4 * 384];
    __shared__ __align__(16) float gls[4 * 512];
    int b0 = blockIdx.x * 4;
    int tid = threadIdx.x;
    for (int i = tid; i < 4 * 384; i += 128) {
        int bb = i / 384, k = i % 384;
        als[i] = (k < 256) ? qstar[(b0 + bb) * 256 + k]
                           : hh[(b0 + bb) * 128 + (k - 256)];
    }
    __syncthreads();
    int g = tid * 4;
    float4 acc[4] = {};
    for (int k = 0; k < 384; k++) {
        float4 w = *(const float4*)&Wt_g[k * 512 + g];
#pragma unroll
        for (int r = 0; r < 4; r++) {
            float a = als[r * 384 + k];
            acc[r].x += a * w.x; acc[r].y += a * w.y;
            acc[r].z += a * w.z; acc[r].w += a * w.w;
        }
    }
    float4 bias;
    bias.x = b_ih[g + 0] + b_hh[g + 0];
    bias.y = b_ih[g + 1] + b_hh[g + 1];
    bias.z = b_ih[g + 2] + b_hh[g + 2];
    bias.w = b_ih[g + 3] + b_hh[g + 3];
#pragma unroll
    for (int r = 0; r < 4; r++) {
        float4 o;
        o.x = acc[r].x + bias.x; o.y = acc[r].y + bias.y;
        o.z = acc[r].z + bias.z; o.w = acc[r].w + bias.w;
        *(float4*)&gls[r * 512 + g] = o;
    }
    __syncthreads();
    // LSTM elementwise: thread t handles feature dd=t for each of 4 rows
    int dd = tid;
#pragma unroll
    for (int r = 0; r < 4; r++) {
        int b = b0 + r;
        float ig = gls[r * 512 + dd];
        float fg = gls[r * 512 + 128 + dd];
        float gg = gls[r * 512 + 256 + dd];
        float og = gls[r * 512 + 384 + dd];
        float c = sigmoidf_(fg) * cc[b * 128 + dd] + sigmoidf_(ig) * tanhf(gg);
        cc[b * 128 + dd] = c;
        float hv = sigmoidf_(og) * tanhf(c);
        hh[b * 128 + dd] = hv;
        qstar[b * 256 + dd] = hv;
    }
}

// ---------------------------------------------------------------------------
// Online-softmax segment attention; when LAST, also computes the prediction
// head out[b] = dot(q_star[b], W_pred) + b_pred (saves the k_pred dispatch).
template <bool LAST>
__global__ __launch_bounds__(128) void k_attn(const float* __restrict__ h,
                                              const float* __restrict__ hh,
                                              const int* __restrict__ seg_ptr,
                                              float* __restrict__ qstar,
                                              const float* __restrict__ W_pred,
                                              const float* __restrict__ b_pred,
                                              float* __restrict__ out) {
    int b = blockIdx.x;
    int g = threadIdx.x >> 5, l = threadIdx.x & 31;
    int s0 = seg_ptr[b], s1 = seg_ptr[b + 1];
    float4 q = *(const float4*)&hh[b * 128 + l * 4];
    float M = -INFINITY, asum = 0.f;
    float4 racc = make_float4(0.f, 0.f, 0.f, 0.f);
    for (int n = s0 + g; n < s1; n += 4) {
        float4 hv = *(const float4*)&h[(size_t)n * 128 + l * 4];
        float d = hv.x * q.x + hv.y * q.y + hv.z * q.z + hv.w * q.w;
        for (int m = 16; m >= 1; m >>= 1) d += __shfl_xor(d, m, 64);
        float newM = fmaxf(M, d);
        float scale = expf(M - newM);
        float a = expf(d - newM);
        asum = asum * scale + a;
        racc.x = racc.x * scale + a * hv.x;
        racc.y = racc.y * scale + a * hv.y;
        racc.z = racc.z * scale + a * hv.z;
        racc.w = racc.w * scale + a * hv.w;
        M = newM;
    }
    __shared__ float smax[4];
    __shared__ float ssum[4];
    __shared__ __align__(16) float sr[4][128];
    if (l == 0) { smax[g] = M; ssum[g] = asum; }
    *(float4*)&sr[g][l * 4] = racc;
    __syncthreads();
    if (g == 0) {
        float Mx = fmaxf(fmaxf(smax[0], smax[1]), fmaxf(smax[2], smax[3]));
        float4 o = make_float4(0.f, 0.f, 0.f, 0.f);
        if (Mx > -INFINITY) {
            float w0 = expf(smax[0] - Mx), w1 = expf(smax[1] - Mx);
            float w2 = expf(smax[2] - Mx), w3 = expf(smax[3] - Mx);
            float tot = ssum[0] * w0 + ssum[1] * w1 + ssum[2] * w2 + ssum[3] * w3;
            float inv = 1.0f / (tot + 1e-16f);
            float4 r0 = *(float4*)&sr[0][l * 4];
            float4 r1 = *(float4*)&sr[1][l * 4];
            float4 r2 = *(float4*)&sr[2][l * 4];
            float4 r3 = *(float4*)&sr[3][l * 4];
            o.x = (r0.x * w0 + r1.x * w1 + r2.x * w2 + r3.x * w3) * inv;
            o.y = (r0.y * w0 + r1.y * w1 + r2.y * w2 + r3.y * w3) * inv;
            o.z = (r0.z * w0 + r1.z * w1 + r2.z * w2 + r3.z * w3) * inv;
            o.w = (r0.w * w0 + r1.w * w1 + r2.w * w2 + r3.w * w3) * inv;
        }
        *(float4*)&qstar[b * 256 + 128 + l * 4] = o;
        if (LAST) {
            float4 wq = *(const float4*)&W_pred[l * 4];
            float4 wr = *(const float4*)&W_pred[128 + l * 4];
            float d = q.x * wq.x + q.y * wq.y + q.z * wq.z + q.w * wq.w
                    + o.x * wr.x + o.y * wr.y + o.z * wr.z + o.w * wr.w;
            for (int m = 16; m >= 1; m >>= 1) d += __shfl_xor(d, m, 64);
            if (l == 0) out[b] = d + b_pred[0];
        }
    }
}

// ---------------------------------------------------------------------------
extern "C" void kernel_launch(void* const* d_in, const int* in_sizes, int n_in,
                              void* d_out, int out_size, void* d_ws, size_t ws_size,
                              hipStream_t stream) {
    const float* x      = (const float*)d_in[0];
    const int*   edge   = (const int*)d_in[1];
    const int*   batch  = (const int*)d_in[2];
    const float* W_in   = (const float*)d_in[3];
    const float* b_in   = (const float*)d_in[4];
    const float* W_ih   = (const float*)d_in[5];
    const float* W_hh   = (const float*)d_in[6];
    const float* b_ih   = (const float*)d_in[7];
    const float* b_hh   = (const float*)d_in[8];
    const float* W_pred = (const float*)d_in[9];
    const float* b_pred = (const float*)d_in[10];
    float* out = (float*)d_out;

    const int* src = edge;
    const int* dst = edge + N_EDGES;

    float* f = (float*)d_ws;
    float* h0    = f;                     f += (size_t)N_NODES * D_HID;
    float* h1    = f;                     f += (size_t)N_NODES * D_HID;
    float* deg_f = f;                     f += N_NODES;
    float* qstar = f;                     f += (size_t)N_B * 256;   // qstar|hh|cc contiguous
    float* hh    = f;                     f += (size_t)N_B * 128;
    float* cc    = f;                     f += (size_t)N_B * 128;
    float* Wt_in = f;                     f += D_INP * D_HID;
    float* Wt_g  = f;                     f += 384 * 512;
    int* ip = (int*)f;
    int* row_ptr = ip;                    ip += N_NODES + 1;
    int* cnt     = ip;                    ip += N_NODES;
    int* esrc    = ip;                    ip += N_EDGES;
    int* seg_ptr = ip;                    ip += N_B + 1;
    int* partials = ip;                   ip += 128;

    // ---- CSR build + seg_ptr + weight transposes (cnt zeroed in transpose)
    k_transpose<<<768, 256, 0, stream>>>(W_in, W_ih, W_hh, Wt_in, Wt_g, cnt);
    k_count<<<(N_EDGES + 255) / 256, 256, 0, stream>>>(dst, cnt);
    k_scan_block<<<SCAN_NB, 512, 0, stream>>>(cnt, row_ptr, partials, deg_f);
    k_scan_part<<<1, 128, 0, stream>>>(partials, row_ptr);
    k_scan_add<<<SCAN_NB, 512, 0, stream>>>(row_ptr, partials, cnt);  // re-zeroes cnt
    k_scatter<<<(N_EDGES + 255) / 256, 256, 0, stream>>>(src, dst, row_ptr, cnt, esrc);
    k_segptr<<<(N_NODES + 255) / 256, 256, 0, stream>>>(batch, seg_ptr);

    // ---- input layer (also zero-inits qstar|hh|cc)
    k_ingemm<<<dim3((N_NODES + 63) / 64, 2), 256, 0, stream>>>(x, Wt_in, b_in, h0, qstar);

    // ---- 4 MPNN steps (ping-pong, ends in h0)
    int mb = (N_NODES + 7) / 8;
    k_mpnn<<<mb, 256, 0, stream>>>(h0, h1, row_ptr, esrc, deg_f);
    k_mpnn<<<mb, 256, 0, stream>>>(h1, h0, row_ptr, esrc, deg_f);
    k_mpnn<<<mb, 256, 0, stream>>>(h0, h1, row_ptr, esrc, deg_f);
    k_mpnn<<<mb, 256, 0, stream>>>(h1, h0, row_ptr, esrc, deg_f);

    // ---- Set2Set: (gates+lstm) fused, attn (last one also does the head)
    for (int step = 0; step < 3; step++) {
        k_gates_lstm<<<N_B / 4, 128, 0, stream>>>(qstar, hh, cc, Wt_g, b_ih, b_hh);
        if (step < 2)
            k_attn<false><<<N_B, 128, 0, stream>>>(h0, hh, seg_ptr, qstar, W_pred, b_pred, out);
        else
            k_attn<true><<<N_B, 128, 0, stream>>>(h0, hh, seg_ptr, qstar, W_pred, b_pred, out);
    }
}